// Round 2
// baseline (450.026 us; speedup 1.0000x reference)
//
#include <hip/hip_runtime.h>
#include <math.h>

#define B_    128
#define T_    24
#define NN    300
#define EE    9000
#define GG    (B_ * T_)
#define GRUH  12
#define OUTF  1200

// ---------------------------------------------------------------------------
// Kernel 1: per-graph EdgeGAT + mean pool, collapsed to scalar S[g].
//   logit_e = leakyrelu(cL*x[src] + cR*x[dst] + cE*ew[e])
//   S[g]    = sum_n ( sum_{e: dst==n} exp(logit_e)*x[src_e] ) / ( sum exp(logit_e) )
// Single edge-parallel pass, LDS float atomics into den/num (no max-shift:
// |logit| <~ 15, exp is safe in fp32; result mathematically identical).
// ---------------------------------------------------------------------------
__global__ __launch_bounds__(256) void gat_pool(
    const float* __restrict__ x, const float* __restrict__ ew,
    const int* __restrict__ src, const int* __restrict__ dst,
    const float* __restrict__ w_node, const float* __restrict__ w_edge,
    const float* __restrict__ attn_l, const float* __restrict__ attn_r,
    const float* __restrict__ attn_e,
    float* __restrict__ S)
{
    __shared__ float xs[NN];
    __shared__ float den[NN];
    __shared__ float num[NN];
    __shared__ float red[4];

    const int g = blockIdx.x;
    const int tid = threadIdx.x;

    // scalar attention constants (tiny, L2-broadcast)
    float cL = 0.f, cR = 0.f, cE = 0.f;
#pragma unroll
    for (int o = 0; o < 4; o++) {
        float wn = w_node[o];
        cL += wn * attn_l[o];
        cR += wn * attn_r[o];
        cE += w_edge[o] * attn_e[o];
    }

    const float* xrow = x + (size_t)g * NN;
    const float* erow = ew + (size_t)g * EE;

    for (int i = tid; i < NN; i += 256) {
        xs[i]  = xrow[i];
        den[i] = 0.f;
        num[i] = 0.f;
    }
    __syncthreads();

    // edge-parallel, fully coalesced: 2250 float4/int4 packs
    const float4* e4 = (const float4*)erow;
    const int4*   s4 = (const int4*)src;
    const int4*   d4 = (const int4*)dst;
    for (int p = tid; p < EE / 4; p += 256) {
        float4 w = e4[p];
        int4 s = s4[p];
        int4 d = d4[p];
#pragma unroll
        for (int k = 0; k < 4; k++) {
            int   si = (k == 0) ? s.x : (k == 1) ? s.y : (k == 2) ? s.z : s.w;
            int   di = (k == 0) ? d.x : (k == 1) ? d.y : (k == 2) ? d.z : d.w;
            float wv = (k == 0) ? w.x : (k == 1) ? w.y : (k == 2) ? w.z : w.w;
            float xsv = xs[si];
            float v = cL * xsv + cR * xs[di] + cE * wv;
            v = (v >= 0.f) ? v : 0.2f * v;
            float ex = __expf(v);
            atomicAdd(&den[di], ex);
            atomicAdd(&num[di], ex * xsv);
        }
    }
    __syncthreads();

    // per-node combine + block reduce
    float acc = 0.f;
    for (int n = tid; n < NN; n += 256) {
        float d = den[n];
        if (d > 0.f) acc += num[n] / d;
    }
    for (int off = 32; off > 0; off >>= 1) acc += __shfl_down(acc, off);
    if ((tid & 63) == 0) red[tid >> 6] = acc;
    __syncthreads();
    if (tid == 0) S[g] = red[0] + red[1] + red[2] + red[3];
}

// ---------------------------------------------------------------------------
// Kernel 2: GRU (24 steps, hidden 12). One wave per batch -> hbuf[b][12].
// pooled[b,t,o] = (S[g]/N) * w_node[o] + gat_bias[o]
// ---------------------------------------------------------------------------
__device__ __forceinline__ float sigmoidf_(float v) { return 1.0f / (1.0f + __expf(-v)); }

__global__ __launch_bounds__(64) void gru_kernel(
    const float* __restrict__ S,
    const float* __restrict__ w_node, const float* __restrict__ gat_bias,
    const float* __restrict__ w_ih, const float* __restrict__ w_hh,
    const float* __restrict__ b_ih, const float* __restrict__ b_hh,
    float* __restrict__ hbuf)
{
    __shared__ float h[GRUH];
    __shared__ float gi_s[36], gh_s[36];

    const int b = blockIdx.x;
    const int lane = threadIdx.x;

    float wn[4], gb[4];
#pragma unroll
    for (int i = 0; i < 4; i++) {
        wn[i] = w_node[i] * (1.0f / (float)NN);
        gb[i] = gat_bias[i];
    }

    float wih[4], whh[12], bih = 0.f, bhh = 0.f;
    if (lane < 36) {
#pragma unroll
        for (int i = 0; i < 4; i++)  wih[i] = w_ih[lane * 4 + i];
#pragma unroll
        for (int j = 0; j < 12; j++) whh[j] = w_hh[lane * 12 + j];
        bih = b_ih[lane];
        bhh = b_hh[lane];
    }
    if (lane < GRUH) h[lane] = 0.f;
    __syncthreads();

    for (int t = 0; t < T_; t++) {
        const float Sg = S[b * T_ + t];
        if (lane < 36) {
            float gi = bih, gh = bhh;
#pragma unroll
            for (int i = 0; i < 4; i++)  gi += (Sg * wn[i] + gb[i]) * wih[i];
#pragma unroll
            for (int j = 0; j < 12; j++) gh += h[j] * whh[j];
            gi_s[lane] = gi;
            gh_s[lane] = gh;
        }
        __syncthreads();
        if (lane < GRUH) {
            float r = sigmoidf_(gi_s[lane] + gh_s[lane]);
            float z = sigmoidf_(gi_s[12 + lane] + gh_s[12 + lane]);
            float n = tanhf(gi_s[24 + lane] + r * gh_s[24 + lane]);
            h[lane] = (1.f - z) * n + z * h[lane];
        }
        __syncthreads();
    }

    if (lane < GRUH) hbuf[b * GRUH + lane] = h[lane];
}

// ---------------------------------------------------------------------------
// Kernel 3: FC (12 -> 1200) per batch, one thread per output element.
// grid = (5, 128): j = bx*256+tid, b = by. 614 KB coalesced writes.
// ---------------------------------------------------------------------------
__global__ __launch_bounds__(256) void fc_kernel(
    const float* __restrict__ hbuf,
    const float* __restrict__ fc_w, const float* __restrict__ fc_b,
    float* __restrict__ out)
{
    __shared__ float hs[GRUH];
    const int b = blockIdx.y;
    const int j = blockIdx.x * 256 + threadIdx.x;

    if (threadIdx.x < GRUH) hs[threadIdx.x] = hbuf[b * GRUH + threadIdx.x];
    __syncthreads();

    if (j < OUTF) {
        float o = fc_b[j];
#pragma unroll
        for (int k = 0; k < GRUH; k++) o += hs[k] * fc_w[j * GRUH + k];
        out[(size_t)b * OUTF + j] = o;
    }
}

// ---------------------------------------------------------------------------
extern "C" void kernel_launch(void* const* d_in, const int* in_sizes, int n_in,
                              void* d_out, int out_size, void* d_ws, size_t ws_size,
                              hipStream_t stream)
{
    const float* x        = (const float*)d_in[0];
    const float* ew       = (const float*)d_in[1];
    const int*   src      = (const int*)d_in[2];
    const int*   dst      = (const int*)d_in[3];
    const float* w_node   = (const float*)d_in[4];
    const float* w_edge   = (const float*)d_in[5];
    const float* attn_l   = (const float*)d_in[6];
    const float* attn_r   = (const float*)d_in[7];
    const float* attn_e   = (const float*)d_in[8];
    const float* gat_bias = (const float*)d_in[9];
    const float* w_ih     = (const float*)d_in[10];
    const float* w_hh     = (const float*)d_in[11];
    const float* b_ih     = (const float*)d_in[12];
    const float* b_hh     = (const float*)d_in[13];
    const float* fc_w     = (const float*)d_in[14];
    const float* fc_b     = (const float*)d_in[15];
    float* out = (float*)d_out;

    // workspace layout
    float* S    = (float*)d_ws;          // GG floats
    float* hbuf = S + GG;                // B_*GRUH floats

    gat_pool<<<GG, 256, 0, stream>>>(x, ew, src, dst, w_node, w_edge,
                                     attn_l, attn_r, attn_e, S);
    gru_kernel<<<B_, 64, 0, stream>>>(S, w_node, gat_bias, w_ih, w_hh,
                                      b_ih, b_hh, hbuf);
    fc_kernel<<<dim3(5, B_), 256, 0, stream>>>(hbuf, fc_w, fc_b, out);
}